// Round 3
// baseline (555.329 us; speedup 1.0000x reference)
//
#include <hip/hip_runtime.h>

#define NN 50000
#define NE 600000

typedef __attribute__((ext_vector_type(8))) short short8;
typedef __attribute__((ext_vector_type(4))) float f32x4;

#define SWZ(row) ((((row) & 7) << 4) ^ (((row) & 8) << 2))

__device__ __forceinline__ float silu_f(float x) { return x / (1.0f + __expf(-x)); }

__device__ __forceinline__ unsigned short f2bf(float f) {
    unsigned u = __builtin_bit_cast(unsigned, f);
    unsigned r = u + 0x7FFFu + ((u >> 16) & 1u);   // RNE
    return (unsigned short)(r >> 16);
}

// ---------------------------------------------------------------------------
// K0: h (fp32) -> h_bf16
// ---------------------------------------------------------------------------
__global__ __launch_bounds__(512) void k_prep(const float* __restrict__ h,
                                              unsigned short* __restrict__ hb)
{
    const int nchunks = NN * 128 / 8;   // 800000
    for (int i = blockIdx.x * blockDim.x + threadIdx.x; i < nchunks;
         i += gridDim.x * blockDim.x) {
        const float4* p = (const float4*)(h + (size_t)i * 8);
        float4 x = p[0], y = p[1];
        short8 v;
        v[0] = f2bf(x.x); v[1] = f2bf(x.y); v[2] = f2bf(x.z); v[3] = f2bf(x.w);
        v[4] = f2bf(y.x); v[5] = f2bf(y.y); v[6] = f2bf(y.z); v[7] = f2bf(y.w);
        *(short8*)(hb + (size_t)i * 8) = v;
    }
}

// ---------------------------------------------------------------------------
// K1: fully fused edge pipeline (edge MLP + coord MLP + both segment sums).
// 8 waves; each wave owns a 16-col N-slice with B-fragments in REGISTERS.
// LDS ~52KB -> 2 blocks/CU (16 waves/CU).
// Per 64-edge tile:
//   stage A1=[h_r,h_c] (bf16, swizzled) + rad/dxyz/rows
//   GEMM1 (K=256) + rank-1 radial + bias -> silu -> A2s (t1)
//   GEMM2 (K=128) -> silu -> ef (nt store) + atomicAdd agg + EF bf16 -> A1s
//   GEMM-c1 (K=128) -> silu -> dot w_c2 -> cross-wave wq reduce
//   tsum/cnt atomics
// ---------------------------------------------------------------------------
__global__ __launch_bounds__(512, 4) void k_edge(
    const unsigned short* __restrict__ hb, const float* __restrict__ coord,
    const int* __restrict__ ei,
    const float* __restrict__ w_e1, const float* __restrict__ b_e1,
    const float* __restrict__ w_e2, const float* __restrict__ b_e2,
    const float* __restrict__ w_c1, const float* __restrict__ b_c1,
    const float* __restrict__ w_c2,
    float* __restrict__ ef, float* __restrict__ agg,
    float* __restrict__ tsum, float* __restrict__ cnt)
{
    __shared__ unsigned short A1s[64 * 256];    // 32768 B  [e][k] swizzled (also EF later)
    __shared__ unsigned short A2s[64 * 128];    // 16384 B  [e][k1] swizzled
    __shared__ float rad[64];
    __shared__ float dxyz[64][3];
    __shared__ int   rows_s[64];
    __shared__ float wqp[8][64];

    const int tid  = threadIdx.x;
    const int wv   = tid >> 6, lane = tid & 63;
    const int l4   = lane >> 4, li = lane & 15;
    const int nwb  = wv * 16;                   // this wave's N-slice base
    const int n    = nwb + li;

    // ---- load this wave's weight B-fragments into registers ----
    short8 bw1[8], bw2[4], bwc[4];
    #pragma unroll
    for (int ks = 0; ks < 8; ++ks) {
        short8 t;
        #pragma unroll
        for (int j = 0; j < 8; ++j) t[j] = f2bf(w_e1[(ks * 32 + l4 * 8 + j) * 128 + n]);
        bw1[ks] = t;
    }
    #pragma unroll
    for (int ks = 0; ks < 4; ++ks) {
        short8 t, u;
        #pragma unroll
        for (int j = 0; j < 8; ++j) {
            t[j] = f2bf(w_e2[(ks * 32 + l4 * 8 + j) * 128 + n]);
            u[j] = f2bf(w_c1[(ks * 32 + l4 * 8 + j) * 128 + n]);
        }
        bw2[ks] = t; bwc[ks] = u;
    }
    const float wradv = w_e1[256 * 128 + n];
    const float b1v = b_e1[n], b2v = b_e2[n], bc1v = b_c1[n], wc2v = w_c2[n];

    const f32x4 z4 = {0.f, 0.f, 0.f, 0.f};

    for (int t = blockIdx.x; t < NE / 64; t += gridDim.x) {
        const int ebase = t * 64;
        // ---- stage indices + radial + coord-diff ----
        if (tid < 64) {
            int e = ebase + tid;
            int r = ei[e], c = ei[NE + e];
            rows_s[tid] = r;
            float dx = coord[r * 3 + 0] - coord[c * 3 + 0];
            float dy = coord[r * 3 + 1] - coord[c * 3 + 1];
            float dz = coord[r * 3 + 2] - coord[c * 3 + 2];
            dxyz[tid][0] = dx; dxyz[tid][1] = dy; dxyz[tid][2] = dz;
            rad[tid] = dx * dx + dy * dy + dz * dz;
        }
        // ---- stage A1: 64 edges x 32 chunks (16B) ----
        {
            int le = tid >> 3;
            int e = ebase + le;
            int r = ei[e], c = ei[NE + e];
            const unsigned short* hr = hb + (size_t)r * 128;
            const unsigned short* hc = hb + (size_t)c * 128;
            #pragma unroll
            for (int i = 0; i < 4; ++i) {
                int chunk = i * 8 + (tid & 7);
                short8 v = (chunk < 16) ? *(const short8*)(hr + chunk * 8)
                                        : *(const short8*)(hc + (chunk - 16) * 8);
                int off = le * 512 + ((chunk * 16) ^ SWZ(le));
                *(short8*)((char*)A1s + off) = v;
            }
        }
        __syncthreads();   // B1

        // ---- GEMM1: [64 x 256] @ [256 x 16] ----
        f32x4 acc[4];
        acc[0] = z4; acc[1] = z4; acc[2] = z4; acc[3] = z4;
        for (int ks = 0; ks < 8; ++ks) {
            const int kb = ks * 64 + l4 * 16;
            #pragma unroll
            for (int mf = 0; mf < 4; ++mf) {
                int row = mf * 16 + li;
                short8 a = *(const short8*)((const char*)A1s + row * 512 + (kb ^ SWZ(row)));
                acc[mf] = __builtin_amdgcn_mfma_f32_16x16x32_bf16(a, bw1[ks], acc[mf], 0, 0, 0);
            }
        }
        // epilogue1: + radial rank-1 + bias, silu -> A2s (t1, bf16 swizzled)
        #pragma unroll
        for (int mf = 0; mf < 4; ++mf)
            #pragma unroll
            for (int r = 0; r < 4; ++r) {
                int row = mf * 16 + l4 * 4 + r;
                float v = silu_f(acc[mf][r] + rad[row] * wradv + b1v);
                int off = row * 256 + ((n * 2) ^ SWZ(row));
                *(unsigned short*)((char*)A2s + off) = f2bf(v);
            }
        __syncthreads();   // B2 (A2s ready; A1s reads done)

        // ---- GEMM2: [64 x 128] @ [128 x 16] ----
        acc[0] = z4; acc[1] = z4; acc[2] = z4; acc[3] = z4;
        for (int ks = 0; ks < 4; ++ks) {
            const int kb = ks * 64 + l4 * 16;
            #pragma unroll
            for (int mf = 0; mf < 4; ++mf) {
                int row = mf * 16 + li;
                short8 a = *(const short8*)((const char*)A2s + row * 256 + (kb ^ SWZ(row)));
                acc[mf] = __builtin_amdgcn_mfma_f32_16x16x32_bf16(a, bw2[ks], acc[mf], 0, 0, 0);
            }
        }
        // epilogue2: silu -> ef (nt), agg atomics, EF bf16 into A1s region
        #pragma unroll
        for (int mf = 0; mf < 4; ++mf)
            #pragma unroll
            for (int r = 0; r < 4; ++r) {
                int row = mf * 16 + l4 * 4 + r;
                int e = ebase + row;
                float v = silu_f(acc[mf][r] + b2v);
                __builtin_nontemporal_store(v, &ef[(size_t)e * 128 + n]);
                atomicAdd(&agg[(size_t)rows_s[row] * 128 + n], v);
                int off = row * 256 + ((n * 2) ^ SWZ(row));
                *(unsigned short*)((char*)A1s + off) = f2bf(v);
            }
        __syncthreads();   // B3 (EF ready; A2s reads done)

        // ---- GEMM-c1: [64 x 128] @ [128 x 16] ----
        acc[0] = z4; acc[1] = z4; acc[2] = z4; acc[3] = z4;
        for (int ks = 0; ks < 4; ++ks) {
            const int kb = ks * 64 + l4 * 16;
            #pragma unroll
            for (int mf = 0; mf < 4; ++mf) {
                int row = mf * 16 + li;
                short8 a = *(const short8*)((const char*)A1s + row * 256 + (kb ^ SWZ(row)));
                acc[mf] = __builtin_amdgcn_mfma_f32_16x16x32_bf16(a, bwc[ks], acc[mf], 0, 0, 0);
            }
        }
        // wq partial: silu(c1)*w_c2, reduce over the 16 lanes of each li-group
        #pragma unroll
        for (int mf = 0; mf < 4; ++mf)
            #pragma unroll
            for (int r = 0; r < 4; ++r) {
                float p = silu_f(acc[mf][r] + bc1v) * wc2v;
                p += __shfl_xor(p, 1); p += __shfl_xor(p, 2);
                p += __shfl_xor(p, 4); p += __shfl_xor(p, 8);
                if (li == 0) wqp[wv][mf * 16 + l4 * 4 + r] = p;
            }
        __syncthreads();   // B4 (wqp ready)

        if (tid < 64) {
            float wq = 0.f;
            #pragma unroll
            for (int w = 0; w < 8; ++w) wq += wqp[w][tid];
            int rr = rows_s[tid];
            atomicAdd(&tsum[rr * 3 + 0], dxyz[tid][0] * wq);
            atomicAdd(&tsum[rr * 3 + 1], dxyz[tid][1] * wq);
            atomicAdd(&tsum[rr * 3 + 2], dxyz[tid][2] * wq);
            atomicAdd(&cnt[rr], 1.0f);
        }
        __syncthreads();   // B5 (protect LDS for next tile)
    }
}

// ---------------------------------------------------------------------------
// K2: fused node MLP.  u = silu([h,agg] @ w_n1 + b_n1);
//     h_new = h + u @ w_n2 + b_n2;  coord_new = coord + tsum/max(cnt,1)
// Same register-weight structure; 64-node tiles (tail-guarded).
// ---------------------------------------------------------------------------
__global__ __launch_bounds__(512, 4) void k_node(
    const unsigned short* __restrict__ hb, const float* __restrict__ h,
    const float* __restrict__ agg,
    const float* __restrict__ w_n1, const float* __restrict__ b_n1,
    const float* __restrict__ w_n2, const float* __restrict__ b_n2,
    const float* __restrict__ coord, const float* __restrict__ tsum,
    const float* __restrict__ cnt,
    float* __restrict__ h_new, float* __restrict__ coord_new)
{
    __shared__ unsigned short As[64 * 256];     // 32768 B
    __shared__ unsigned short Us[64 * 128];     // 16384 B

    const int tid  = threadIdx.x;
    const int wv   = tid >> 6, lane = tid & 63;
    const int l4   = lane >> 4, li = lane & 15;
    const int n    = wv * 16 + li;

    short8 bw1[8], bw2[4];
    #pragma unroll
    for (int ks = 0; ks < 8; ++ks) {
        short8 t;
        #pragma unroll
        for (int j = 0; j < 8; ++j) t[j] = f2bf(w_n1[(ks * 32 + l4 * 8 + j) * 128 + n]);
        bw1[ks] = t;
    }
    #pragma unroll
    for (int ks = 0; ks < 4; ++ks) {
        short8 t;
        #pragma unroll
        for (int j = 0; j < 8; ++j) t[j] = f2bf(w_n2[(ks * 32 + l4 * 8 + j) * 128 + n]);
        bw2[ks] = t;
    }
    const float b1v = b_n1[n], b2v = b_n2[n];

    const f32x4 z4 = {0.f, 0.f, 0.f, 0.f};
    const int ntiles = (NN + 63) / 64;          // 782

    for (int t = blockIdx.x; t < ntiles; t += gridDim.x) {
        const int nbase = t * 64;
        // stage [hb | bf16(agg)] : 64 nodes x 32 chunks
        {
            int ln = tid >> 3;
            int node = nbase + ln;
            #pragma unroll
            for (int i = 0; i < 4; ++i) {
                int chunk = i * 8 + (tid & 7);
                short8 v;
                if (node < NN) {
                    if (chunk < 16) {
                        v = *(const short8*)(hb + (size_t)node * 128 + chunk * 8);
                    } else {
                        const float4* p = (const float4*)(agg + (size_t)node * 128 + (chunk - 16) * 8);
                        float4 x = p[0], y = p[1];
                        v[0] = f2bf(x.x); v[1] = f2bf(x.y); v[2] = f2bf(x.z); v[3] = f2bf(x.w);
                        v[4] = f2bf(y.x); v[5] = f2bf(y.y); v[6] = f2bf(y.z); v[7] = f2bf(y.w);
                    }
                } else v = (short8)0;
                int off = ln * 512 + ((chunk * 16) ^ SWZ(ln));
                *(short8*)((char*)As + off) = v;
            }
        }
        __syncthreads();

        // GEMM1: K=256
        f32x4 acc[4];
        acc[0] = z4; acc[1] = z4; acc[2] = z4; acc[3] = z4;
        for (int ks = 0; ks < 8; ++ks) {
            const int kb = ks * 64 + l4 * 16;
            #pragma unroll
            for (int mf = 0; mf < 4; ++mf) {
                int row = mf * 16 + li;
                short8 a = *(const short8*)((const char*)As + row * 512 + (kb ^ SWZ(row)));
                acc[mf] = __builtin_amdgcn_mfma_f32_16x16x32_bf16(a, bw1[ks], acc[mf], 0, 0, 0);
            }
        }
        #pragma unroll
        for (int mf = 0; mf < 4; ++mf)
            #pragma unroll
            for (int r = 0; r < 4; ++r) {
                int row = mf * 16 + l4 * 4 + r;
                float v = silu_f(acc[mf][r] + b1v);
                int off = row * 256 + ((n * 2) ^ SWZ(row));
                *(unsigned short*)((char*)Us + off) = f2bf(v);
            }
        __syncthreads();

        // GEMM2: K=128
        acc[0] = z4; acc[1] = z4; acc[2] = z4; acc[3] = z4;
        for (int ks = 0; ks < 4; ++ks) {
            const int kb = ks * 64 + l4 * 16;
            #pragma unroll
            for (int mf = 0; mf < 4; ++mf) {
                int row = mf * 16 + li;
                short8 a = *(const short8*)((const char*)Us + row * 256 + (kb ^ SWZ(row)));
                acc[mf] = __builtin_amdgcn_mfma_f32_16x16x32_bf16(a, bw2[ks], acc[mf], 0, 0, 0);
            }
        }
        #pragma unroll
        for (int mf = 0; mf < 4; ++mf)
            #pragma unroll
            for (int r = 0; r < 4; ++r) {
                int row = mf * 16 + l4 * 4 + r;
                int node = nbase + row;
                if (node < NN) {
                    float v = acc[mf][r] + b2v + h[(size_t)node * 128 + n];
                    __builtin_nontemporal_store(v, &h_new[(size_t)node * 128 + n]);
                }
            }
        if (tid < 64) {
            int node = nbase + tid;
            if (node < NN) {
                float m = fmaxf(cnt[node], 1.0f);
                coord_new[node * 3 + 0] = coord[node * 3 + 0] + tsum[node * 3 + 0] / m;
                coord_new[node * 3 + 1] = coord[node * 3 + 1] + tsum[node * 3 + 1] / m;
                coord_new[node * 3 + 2] = coord[node * 3 + 2] + tsum[node * 3 + 2] / m;
            }
        }
        __syncthreads();
    }
}

extern "C" void kernel_launch(void* const* d_in, const int* in_sizes, int n_in,
                              void* d_out, int out_size, void* d_ws, size_t ws_size,
                              hipStream_t stream)
{
    const float* h     = (const float*)d_in[0];
    const float* coord = (const float*)d_in[1];
    const int*   ei    = (const int*)d_in[2];
    const float* w_e1  = (const float*)d_in[3];
    const float* b_e1  = (const float*)d_in[4];
    const float* w_e2  = (const float*)d_in[5];
    const float* b_e2  = (const float*)d_in[6];
    const float* w_n1  = (const float*)d_in[7];
    const float* b_n1  = (const float*)d_in[8];
    const float* w_n2  = (const float*)d_in[9];
    const float* b_n2  = (const float*)d_in[10];
    const float* w_c1  = (const float*)d_in[11];
    const float* b_c1  = (const float*)d_in[12];
    const float* w_c2  = (const float*)d_in[13];

    float* h_new     = (float*)d_out;
    float* coord_new = h_new + (size_t)NN * 128;
    float* ef        = coord_new + (size_t)NN * 3;

    float*          agg  = (float*)d_ws;                      // [NN*128] f32
    float*          tsum = agg + (size_t)NN * 128;            // [NN*3]
    float*          cnt  = tsum + (size_t)NN * 3;             // [NN]
    unsigned short* hb   = (unsigned short*)(cnt + NN);       // [NN*128] bf16

    hipMemsetAsync(agg, 0, ((size_t)NN * 128 + (size_t)NN * 3 + NN) * sizeof(float), stream);

    k_prep<<<1024, 512, 0, stream>>>(h, hb);
    k_edge<<<512, 512, 0, stream>>>(hb, coord, ei, w_e1, b_e1, w_e2, b_e2,
                                    w_c1, b_c1, w_c2, ef, agg, tsum, cnt);
    k_node<<<512, 512, 0, stream>>>(hb, h, agg, w_n1, b_n1, w_n2, b_n2,
                                    coord, tsum, cnt, h_new, coord_new);
}

// Round 4
// 544.415 us; speedup vs baseline: 1.0200x; 1.0200x over previous
//
#include <hip/hip_runtime.h>

#define NN 50000
#define NE 600000

typedef __attribute__((ext_vector_type(8))) short short8;
typedef __attribute__((ext_vector_type(4))) float f32x4;

#define SWZ(row) ((((row) & 7) << 4) ^ (((row) & 8) << 2))

__device__ __forceinline__ float silu_f(float x) { return x / (1.0f + __expf(-x)); }

__device__ __forceinline__ unsigned short f2bf(float f) {
    unsigned u = __builtin_bit_cast(unsigned, f);
    unsigned r = u + 0x7FFFu + ((u >> 16) & 1u);   // RNE
    return (unsigned short)(r >> 16);
}

// Barrier that drains ONLY LDS ops (lgkmcnt), leaving global stores/atomics
// in flight (vmcnt not drained). This is the m201/HK counted-wait pattern:
// __syncthreads would emit s_waitcnt vmcnt(0) before s_barrier and stall on
// every outstanding atomic.
__device__ __forceinline__ void lds_barrier() {
    asm volatile("s_waitcnt lgkmcnt(0)" ::: "memory");
    __builtin_amdgcn_s_barrier();
    asm volatile("" ::: "memory");
}

// ---------------------------------------------------------------------------
// K0: h (fp32) -> h_bf16
// ---------------------------------------------------------------------------
__global__ __launch_bounds__(512) void k_prep(const float* __restrict__ h,
                                              unsigned short* __restrict__ hb)
{
    const int nchunks = NN * 128 / 8;   // 800000
    for (int i = blockIdx.x * blockDim.x + threadIdx.x; i < nchunks;
         i += gridDim.x * blockDim.x) {
        const float4* p = (const float4*)(h + (size_t)i * 8);
        float4 x = p[0], y = p[1];
        short8 v;
        v[0] = f2bf(x.x); v[1] = f2bf(x.y); v[2] = f2bf(x.z); v[3] = f2bf(x.w);
        v[4] = f2bf(y.x); v[5] = f2bf(y.y); v[6] = f2bf(y.z); v[7] = f2bf(y.w);
        *(short8*)(hb + (size_t)i * 8) = v;
    }
}

// ---------------------------------------------------------------------------
// K1: fully fused edge pipeline. 8 waves, weights in registers, 64-edge tiles.
// 4 lgkm-only barriers per tile; atomics/stores stay in flight across them.
// ---------------------------------------------------------------------------
__global__ __launch_bounds__(512, 4) void k_edge(
    const unsigned short* __restrict__ hb, const float* __restrict__ coord,
    const int* __restrict__ ei,
    const float* __restrict__ w_e1, const float* __restrict__ b_e1,
    const float* __restrict__ w_e2, const float* __restrict__ b_e2,
    const float* __restrict__ w_c1, const float* __restrict__ b_c1,
    const float* __restrict__ w_c2,
    float* __restrict__ ef, float* __restrict__ agg,
    float* __restrict__ tsum, float* __restrict__ cnt)
{
    __shared__ unsigned short A1s[64 * 256];    // 32768 B  (h-pair; later EF bf16)
    __shared__ unsigned short A2s[64 * 128];    // 16384 B  (t1 bf16)
    __shared__ float rad[64];
    __shared__ float dxyz[64][3];
    __shared__ int   rows_s[64];
    __shared__ float wqp[8][64];

    const int tid  = threadIdx.x;
    const int wv   = tid >> 6, lane = tid & 63;
    const int l4   = lane >> 4, li = lane & 15;
    const int n    = wv * 16 + li;              // this wave's output column

    // ---- weight B-fragments -> registers ----
    short8 bw1[8], bw2[4], bwc[4];
    #pragma unroll
    for (int ks = 0; ks < 8; ++ks) {
        short8 t;
        #pragma unroll
        for (int j = 0; j < 8; ++j) t[j] = f2bf(w_e1[(ks * 32 + l4 * 8 + j) * 128 + n]);
        bw1[ks] = t;
    }
    #pragma unroll
    for (int ks = 0; ks < 4; ++ks) {
        short8 t, u;
        #pragma unroll
        for (int j = 0; j < 8; ++j) {
            t[j] = f2bf(w_e2[(ks * 32 + l4 * 8 + j) * 128 + n]);
            u[j] = f2bf(w_c1[(ks * 32 + l4 * 8 + j) * 128 + n]);
        }
        bw2[ks] = t; bwc[ks] = u;
    }
    const float wradv = w_e1[256 * 128 + n];
    const float b1v = b_e1[n], b2v = b_e2[n], bc1v = b_c1[n], wc2v = w_c2[n];

    const f32x4 z4 = {0.f, 0.f, 0.f, 0.f};

    for (int t = blockIdx.x; t < NE / 64; t += gridDim.x) {
        const int ebase = t * 64;
        // ---- stage indices + radial + coord-diff ----
        if (tid < 64) {
            int e = ebase + tid;
            int r = ei[e], c = ei[NE + e];
            rows_s[tid] = r;
            float dx = coord[r * 3 + 0] - coord[c * 3 + 0];
            float dy = coord[r * 3 + 1] - coord[c * 3 + 1];
            float dz = coord[r * 3 + 2] - coord[c * 3 + 2];
            dxyz[tid][0] = dx; dxyz[tid][1] = dy; dxyz[tid][2] = dz;
            rad[tid] = dx * dx + dy * dy + dz * dz;
        }
        // ---- stage A1: 64 edges x 32 chunks (16B) ----
        {
            int le = tid >> 3;
            int e = ebase + le;
            int r = ei[e], c = ei[NE + e];
            const unsigned short* hr = hb + (size_t)r * 128;
            const unsigned short* hc = hb + (size_t)c * 128;
            #pragma unroll
            for (int i = 0; i < 4; ++i) {
                int chunk = i * 8 + (tid & 7);
                short8 v = (chunk < 16) ? *(const short8*)(hr + chunk * 8)
                                        : *(const short8*)(hc + (chunk - 16) * 8);
                int off = le * 512 + ((chunk * 16) ^ SWZ(le));
                *(short8*)((char*)A1s + off) = v;
            }
        }
        lds_barrier();   // B1: A1s/rad/rows ready

        // ---- GEMM1: [64 x 256] @ [256 x 16] ----
        f32x4 acc[4];
        acc[0] = z4; acc[1] = z4; acc[2] = z4; acc[3] = z4;
        for (int ks = 0; ks < 8; ++ks) {
            const int kb = ks * 64 + l4 * 16;
            #pragma unroll
            for (int mf = 0; mf < 4; ++mf) {
                int row = mf * 16 + li;
                short8 a = *(const short8*)((const char*)A1s + row * 512 + (kb ^ SWZ(row)));
                acc[mf] = __builtin_amdgcn_mfma_f32_16x16x32_bf16(a, bw1[ks], acc[mf], 0, 0, 0);
            }
        }
        // epilogue1: + radial rank-1 + bias, silu -> A2s (t1, bf16 swizzled)
        #pragma unroll
        for (int mf = 0; mf < 4; ++mf)
            #pragma unroll
            for (int r = 0; r < 4; ++r) {
                int row = mf * 16 + l4 * 4 + r;
                float v = silu_f(acc[mf][r] + rad[row] * wradv + b1v);
                int off = row * 256 + ((n * 2) ^ SWZ(row));
                *(unsigned short*)((char*)A2s + off) = f2bf(v);
            }
        lds_barrier();   // B2: A2s ready; A1s reads done

        // ---- GEMM2: [64 x 128] @ [128 x 16] ----
        acc[0] = z4; acc[1] = z4; acc[2] = z4; acc[3] = z4;
        for (int ks = 0; ks < 4; ++ks) {
            const int kb = ks * 64 + l4 * 16;
            #pragma unroll
            for (int mf = 0; mf < 4; ++mf) {
                int row = mf * 16 + li;
                short8 a = *(const short8*)((const char*)A2s + row * 256 + (kb ^ SWZ(row)));
                acc[mf] = __builtin_amdgcn_mfma_f32_16x16x32_bf16(a, bw2[ks], acc[mf], 0, 0, 0);
            }
        }
        // epilogue2: EF bf16 -> A1s (LDS first so lgkm work starts early),
        // then ef nt-store + agg atomics (left in flight across B3).
        #pragma unroll
        for (int mf = 0; mf < 4; ++mf)
            #pragma unroll
            for (int r = 0; r < 4; ++r) {
                int row = mf * 16 + l4 * 4 + r;
                int e = ebase + row;
                float v = silu_f(acc[mf][r] + b2v);
                int off = row * 256 + ((n * 2) ^ SWZ(row));
                *(unsigned short*)((char*)A1s + off) = f2bf(v);
                __builtin_nontemporal_store(v, &ef[(size_t)e * 128 + n]);
                atomicAdd(&agg[(size_t)rows_s[row] * 128 + n], v);
            }
        lds_barrier();   // B3: EF(A1s) ready; A2s reads done

        // ---- GEMM-c1: [64 x 128] @ [128 x 16] ----
        acc[0] = z4; acc[1] = z4; acc[2] = z4; acc[3] = z4;
        for (int ks = 0; ks < 4; ++ks) {
            const int kb = ks * 64 + l4 * 16;
            #pragma unroll
            for (int mf = 0; mf < 4; ++mf) {
                int row = mf * 16 + li;
                short8 a = *(const short8*)((const char*)A1s + row * 256 + (kb ^ SWZ(row)));
                acc[mf] = __builtin_amdgcn_mfma_f32_16x16x32_bf16(a, bwc[ks], acc[mf], 0, 0, 0);
            }
        }
        // wq partials: silu(c1)*w_c2, reduce over 16 lanes
        #pragma unroll
        for (int mf = 0; mf < 4; ++mf)
            #pragma unroll
            for (int r = 0; r < 4; ++r) {
                float p = silu_f(acc[mf][r] + bc1v) * wc2v;
                p += __shfl_xor(p, 1); p += __shfl_xor(p, 2);
                p += __shfl_xor(p, 4); p += __shfl_xor(p, 8);
                if (li == 0) wqp[wv][mf * 16 + l4 * 4 + r] = p;
            }
        lds_barrier();   // B4: wqp ready; A1s reads done (next stage may overwrite)

        if (tid < 64) {
            float wq = 0.f;
            #pragma unroll
            for (int w = 0; w < 8; ++w) wq += wqp[w][tid];
            int rr = rows_s[tid];
            atomicAdd(&tsum[rr * 3 + 0], dxyz[tid][0] * wq);
            atomicAdd(&tsum[rr * 3 + 1], dxyz[tid][1] * wq);
            atomicAdd(&tsum[rr * 3 + 2], dxyz[tid][2] * wq);
            atomicAdd(&cnt[rr], 1.0f);
        }
        // no B5: rows_s/dxyz re-written only by the same tid<64 threads
        // (program order); A1s stage writes are safe after B4; wqp next write
        // is after B3(t+1) which all threads' reads precede via B1(t+1).
    }
}

// ---------------------------------------------------------------------------
// K2: fused node MLP. 2 lgkm-only barriers per tile.
// ---------------------------------------------------------------------------
__global__ __launch_bounds__(512, 4) void k_node(
    const unsigned short* __restrict__ hb, const float* __restrict__ h,
    const float* __restrict__ agg,
    const float* __restrict__ w_n1, const float* __restrict__ b_n1,
    const float* __restrict__ w_n2, const float* __restrict__ b_n2,
    const float* __restrict__ coord, const float* __restrict__ tsum,
    const float* __restrict__ cnt,
    float* __restrict__ h_new, float* __restrict__ coord_new)
{
    __shared__ unsigned short As[64 * 256];     // 32768 B
    __shared__ unsigned short Us[64 * 128];     // 16384 B

    const int tid  = threadIdx.x;
    const int wv   = tid >> 6, lane = tid & 63;
    const int l4   = lane >> 4, li = lane & 15;
    const int n    = wv * 16 + li;

    short8 bw1[8], bw2[4];
    #pragma unroll
    for (int ks = 0; ks < 8; ++ks) {
        short8 t;
        #pragma unroll
        for (int j = 0; j < 8; ++j) t[j] = f2bf(w_n1[(ks * 32 + l4 * 8 + j) * 128 + n]);
        bw1[ks] = t;
    }
    #pragma unroll
    for (int ks = 0; ks < 4; ++ks) {
        short8 t;
        #pragma unroll
        for (int j = 0; j < 8; ++j) t[j] = f2bf(w_n2[(ks * 32 + l4 * 8 + j) * 128 + n]);
        bw2[ks] = t;
    }
    const float b1v = b_n1[n], b2v = b_n2[n];

    const f32x4 z4 = {0.f, 0.f, 0.f, 0.f};
    const int ntiles = (NN + 63) / 64;          // 782

    for (int t = blockIdx.x; t < ntiles; t += gridDim.x) {
        const int nbase = t * 64;
        {
            int ln = tid >> 3;
            int node = nbase + ln;
            #pragma unroll
            for (int i = 0; i < 4; ++i) {
                int chunk = i * 8 + (tid & 7);
                short8 v;
                if (node < NN) {
                    if (chunk < 16) {
                        v = *(const short8*)(hb + (size_t)node * 128 + chunk * 8);
                    } else {
                        const float4* p = (const float4*)(agg + (size_t)node * 128 + (chunk - 16) * 8);
                        float4 x = p[0], y = p[1];
                        v[0] = f2bf(x.x); v[1] = f2bf(x.y); v[2] = f2bf(x.z); v[3] = f2bf(x.w);
                        v[4] = f2bf(y.x); v[5] = f2bf(y.y); v[6] = f2bf(y.z); v[7] = f2bf(y.w);
                    }
                } else v = (short8)0;
                int off = ln * 512 + ((chunk * 16) ^ SWZ(ln));
                *(short8*)((char*)As + off) = v;
            }
        }
        lds_barrier();   // B1

        // GEMM1: K=256
        f32x4 acc[4];
        acc[0] = z4; acc[1] = z4; acc[2] = z4; acc[3] = z4;
        for (int ks = 0; ks < 8; ++ks) {
            const int kb = ks * 64 + l4 * 16;
            #pragma unroll
            for (int mf = 0; mf < 4; ++mf) {
                int row = mf * 16 + li;
                short8 a = *(const short8*)((const char*)As + row * 512 + (kb ^ SWZ(row)));
                acc[mf] = __builtin_amdgcn_mfma_f32_16x16x32_bf16(a, bw1[ks], acc[mf], 0, 0, 0);
            }
        }
        #pragma unroll
        for (int mf = 0; mf < 4; ++mf)
            #pragma unroll
            for (int r = 0; r < 4; ++r) {
                int row = mf * 16 + l4 * 4 + r;
                float v = silu_f(acc[mf][r] + b1v);
                int off = row * 256 + ((n * 2) ^ SWZ(row));
                *(unsigned short*)((char*)Us + off) = f2bf(v);
            }
        lds_barrier();   // B2: Us ready; As reads done

        // GEMM2: K=128
        acc[0] = z4; acc[1] = z4; acc[2] = z4; acc[3] = z4;
        for (int ks = 0; ks < 4; ++ks) {
            const int kb = ks * 64 + l4 * 16;
            #pragma unroll
            for (int mf = 0; mf < 4; ++mf) {
                int row = mf * 16 + li;
                short8 a = *(const short8*)((const char*)Us + row * 256 + (kb ^ SWZ(row)));
                acc[mf] = __builtin_amdgcn_mfma_f32_16x16x32_bf16(a, bw2[ks], acc[mf], 0, 0, 0);
            }
        }
        #pragma unroll
        for (int mf = 0; mf < 4; ++mf)
            #pragma unroll
            for (int r = 0; r < 4; ++r) {
                int row = mf * 16 + l4 * 4 + r;
                int node = nbase + row;
                if (node < NN) {
                    float v = acc[mf][r] + b2v + h[(size_t)node * 128 + n];
                    __builtin_nontemporal_store(v, &h_new[(size_t)node * 128 + n]);
                }
            }
        if (tid < 64) {
            int node = nbase + tid;
            if (node < NN) {
                float m = fmaxf(cnt[node], 1.0f);
                coord_new[node * 3 + 0] = coord[node * 3 + 0] + tsum[node * 3 + 0] / m;
                coord_new[node * 3 + 1] = coord[node * 3 + 1] + tsum[node * 3 + 1] / m;
                coord_new[node * 3 + 2] = coord[node * 3 + 2] + tsum[node * 3 + 2] / m;
            }
        }
        // no trailing barrier: next stage writes As, which GEMM2 never reads;
        // Us(t+1) writes happen after B1(t+1) which orders all prior reads.
    }
}

extern "C" void kernel_launch(void* const* d_in, const int* in_sizes, int n_in,
                              void* d_out, int out_size, void* d_ws, size_t ws_size,
                              hipStream_t stream)
{
    const float* h     = (const float*)d_in[0];
    const float* coord = (const float*)d_in[1];
    const int*   ei    = (const int*)d_in[2];
    const float* w_e1  = (const float*)d_in[3];
    const float* b_e1  = (const float*)d_in[4];
    const float* w_e2  = (const float*)d_in[5];
    const float* b_e2  = (const float*)d_in[6];
    const float* w_n1  = (const float*)d_in[7];
    const float* b_n1  = (const float*)d_in[8];
    const float* w_n2  = (const float*)d_in[9];
    const float* b_n2  = (const float*)d_in[10];
    const float* w_c1  = (const float*)d_in[11];
    const float* b_c1  = (const float*)d_in[12];
    const float* w_c2  = (const float*)d_in[13];

    float* h_new     = (float*)d_out;
    float* coord_new = h_new + (size_t)NN * 128;
    float* ef        = coord_new + (size_t)NN * 3;

    float*          agg  = (float*)d_ws;                      // [NN*128] f32
    float*          tsum = agg + (size_t)NN * 128;            // [NN*3]
    float*          cnt  = tsum + (size_t)NN * 3;             // [NN]
    unsigned short* hb   = (unsigned short*)(cnt + NN);       // [NN*128] bf16

    hipMemsetAsync(agg, 0, ((size_t)NN * 128 + (size_t)NN * 3 + NN) * sizeof(float), stream);

    k_prep<<<1024, 512, 0, stream>>>(h, hb);
    k_edge<<<512, 512, 0, stream>>>(hb, coord, ei, w_e1, b_e1, w_e2, b_e2,
                                    w_c1, b_c1, w_c2, ef, agg, tsum, cnt);
    k_node<<<512, 512, 0, stream>>>(hb, h, agg, w_n1, b_n1, w_n2, b_n2,
                                    coord, tsum, cnt, h_new, coord_new);
}